// Round 4
// baseline (134.813 us; speedup 1.0000x reference)
//
#include <hip/hip_runtime.h>

// FFM pairwise interaction: out[b] = sum_{i<j} sum_k in[b,i,j,k] * in[b,j,i,k]
// B=8192, F=39, K=16, fp32. Memory-bound; fetch floor ~797 MB.
//
// R1/R3 structure (max occupancy, each byte fetched from HBM exactly once),
// plus: fixed-trip main loop (11 iters) with 2-deep software pipeline of
// {table-read -> address -> global load}, nontemporal x-loads, separate tail.

#define FF    39
#define KK    16
#define NPAIR (FF * (FF - 1) / 2)   // 741
#define ITEMS (NPAIR * 4)           // 2964 float4 items per batch
#define SLICE (FF * FF * KK)        // 24336 floats per batch
#define NTHR  256
#define MAIN_ITERS 11               // 11*256 = 2816 items
#define TAIL (ITEMS - MAIN_ITERS * NTHR)  // 148

using f32x4 = __attribute__((ext_vector_type(4))) float;

__global__ __launch_bounds__(NTHR) void ffm_kernel(const float* __restrict__ in,
                                                   float* __restrict__ out,
                                                   int nbatch) {
    __shared__ int xoffB[NPAIR];   // byte offset of block [i,j,0]
    __shared__ int yoffB[NPAIR];   // byte offset of block [j,i,0]
    __shared__ float red[NTHR / 64];

    const int tid = threadIdx.x;

    // Pair -> byte-offset tables (once per block).
    for (int p = tid; p < NPAIR; p += NTHR) {
        int i = (int)((77.0f - sqrtf((float)(5929 - 8 * p))) * 0.5f);
        while (i * (77 - i) / 2 > p) --i;
        while ((i + 1) * (76 - i) / 2 <= p) ++i;
        const int j = i + 1 + (p - i * (77 - i) / 2);
        xoffB[p] = (i * FF + j) * (KK * 4);
        yoffB[p] = (j * FF + i) * (KK * 4);
    }
    __syncthreads();

    const int b = blockIdx.x;
    if (b >= nbatch) return;
    const char* base = (const char*)(in + (size_t)b * SLICE);

    // Main loop: item m_k = tid + 256k  =>  qb const, p advances by 64.
    const int qb = (tid & 3) * 16;
    int p = tid >> 2;

    float acc = 0.f;
    f32x4 x = *reinterpret_cast<const f32x4*>(base + xoffB[p] + qb);
    f32x4 y = *reinterpret_cast<const f32x4*>(base + yoffB[p] + qb);

    #pragma unroll
    for (int k = 0; k < MAIN_ITERS - 1; ++k) {
        const int p2 = p + 64;
        const int xo2 = xoffB[p2] + qb;
        const int yo2 = yoffB[p2] + qb;
        const f32x4 x2 = __builtin_nontemporal_load(
            reinterpret_cast<const f32x4*>(base + xo2));
        const f32x4 y2 = *reinterpret_cast<const f32x4*>(base + yo2);
        acc += x[0] * y[0] + x[1] * y[1] + x[2] * y[2] + x[3] * y[3];
        x = x2; y = y2; p = p2;
    }
    acc += x[0] * y[0] + x[1] * y[1] + x[2] * y[2] + x[3] * y[3];

    // Tail: items 2816 .. 2963 (148 threads active).
    if (tid < TAIL) {
        const int m = MAIN_ITERS * NTHR + tid;
        const int pt = m >> 2;
        const int qt = (m & 3) * 16;
        const f32x4 xt = *reinterpret_cast<const f32x4*>(base + xoffB[pt] + qt);
        const f32x4 yt = *reinterpret_cast<const f32x4*>(base + yoffB[pt] + qt);
        acc += xt[0] * yt[0] + xt[1] * yt[1] + xt[2] * yt[2] + xt[3] * yt[3];
    }

    // 256 -> 1 reduce.
    #pragma unroll
    for (int off = 32; off > 0; off >>= 1)
        acc += __shfl_down(acc, off, 64);
    const int wave = tid >> 6;
    if ((tid & 63) == 0) red[wave] = acc;
    __syncthreads();
    if (tid == 0) {
        float s = 0.f;
        #pragma unroll
        for (int w = 0; w < NTHR / 64; ++w) s += red[w];
        out[b] = s;
    }
}

extern "C" void kernel_launch(void* const* d_in, const int* in_sizes, int n_in,
                              void* d_out, int out_size, void* d_ws, size_t ws_size,
                              hipStream_t stream) {
    const float* in = (const float*)d_in[0];
    float* out = (float*)d_out;
    const int nbatch = out_size;  // 8192

    ffm_kernel<<<dim3(nbatch), dim3(NTHR), 0, stream>>>(in, out, nbatch);
}